// Round 1
// baseline (1664.103 us; speedup 1.0000x reference)
//
#include <hip/hip_runtime.h>

#define D 128
constexpr int V_N    = 100000;
constexpr int E_N    = 600000;
constexpr int HALF_E = E_N / 2;
constexpr int NREL2  = 100;
constexpr int NBUCK  = 2 * NREL2;   // 200 edge buckets; M index 200 = self-loop
constexpr float BN_EPS_F = 1e-5f;

// ---------------- workspace layout (bytes) ----------------
constexpr size_t M_CNT    = 201ull * D * D;              // 201 matrices of 128x128 f32
constexpr size_t M_OFF    = 0;
constexpr size_t SS_OFF   = M_CNT * 4;                   // sorted src (int[E])
constexpr size_t SD_OFF   = SS_OFF + (size_t)E_N * 4;    // sorted dst
constexpr size_t SN_OFF   = SD_OFF + (size_t)E_N * 4;    // sorted norm
constexpr size_t ZERO_OFF = SN_OFF + (size_t)E_N * 4;    // zeroed every launch:
constexpr size_t CNT_OFF  = ZERO_OFF;                    //   counts[200] int (pad to 1024B)
constexpr size_t CS_OFF   = ZERO_OFF + 1024;             //   colsum[128] f32
constexpr size_t CQ_OFF   = CS_OFF + 512;                //   colsq[128] f32
constexpr size_t ZERO_BYTES = 2048;
constexpr size_t ST_OFF   = ZERO_OFF + ZERO_BYTES;       // starts[201] int (written by scan)
constexpr size_t CUR_OFF  = ST_OFF + 1024;               // cursors[200] int
// total ~20.4 MB

// ---------------- sort: histogram ----------------
__global__ void k_hist(const int* __restrict__ etype, int* __restrict__ counts) {
    __shared__ int h[NBUCK];
    for (int i = threadIdx.x; i < NBUCK; i += blockDim.x) h[i] = 0;
    __syncthreads();
    int e = blockIdx.x * blockDim.x + threadIdx.x;
    if (e < E_N) {
        int b = etype[e] + (e < HALF_E ? 0 : NREL2);
        atomicAdd(&h[b], 1);
    }
    __syncthreads();
    for (int i = threadIdx.x; i < NBUCK; i += blockDim.x)
        if (h[i]) atomicAdd(&counts[i], h[i]);
}

// ---------------- sort: exclusive scan (200 entries, trivial) ----------------
__global__ void k_scan(const int* __restrict__ counts, int* __restrict__ starts,
                       int* __restrict__ cursor) {
    if (threadIdx.x == 0) {
        int acc = 0;
        for (int i = 0; i < NBUCK; i++) { starts[i] = acc; cursor[i] = acc; acc += counts[i]; }
        starts[NBUCK] = acc;
    }
}

// ---------------- sort: scatter edge records ----------------
__global__ void k_scatter(const int* __restrict__ src, const int* __restrict__ dst,
                          const float* __restrict__ norm, const int* __restrict__ etype,
                          int* __restrict__ cursor, int* __restrict__ ssrc,
                          int* __restrict__ sdst, float* __restrict__ snorm) {
    int e = blockIdx.x * blockDim.x + threadIdx.x;
    if (e >= E_N) return;
    int b = etype[e] + (e < HALF_E ? 0 : NREL2);
    int p = atomicAdd(&cursor[b], 1);
    ssrc[p] = src[e]; sdst[p] = dst[e]; snorm[p] = norm[e];
}

// ---------------- build M matrices: M[b][j][o] = sum_k r[(j+k)%128] * W[k][o] ----------------
// blocks 0..99: rel[b], in_w ; 100..199: rel[b-100], out_w ; 200: loop_rel, loop_w
__global__ void k_build_M(const float* __restrict__ rel, const float* __restrict__ in_w,
                          const float* __restrict__ out_w, const float* __restrict__ loop_rel,
                          const float* __restrict__ loop_w, float* __restrict__ M_all) {
    extern __shared__ float smem[];
    float* sW = smem;            // 128*128
    float* sR = smem + D * D;    // 256 (r duplicated to avoid %128)
    int b = blockIdx.x;
    const float* r = (b < NREL2) ? rel + (size_t)b * D
                   : (b < NBUCK) ? rel + (size_t)(b - NREL2) * D : loop_rel;
    const float* W = (b < NREL2) ? in_w : (b < NBUCK) ? out_w : loop_w;
    for (int i = threadIdx.x; i < D * D; i += blockDim.x) sW[i] = W[i];
    for (int i = threadIdx.x; i < D; i += blockDim.x) { float v = r[i]; sR[i] = v; sR[i + D] = v; }
    __syncthreads();
    int o  = threadIdx.x & 127;
    int jg = threadIdx.x >> 7;   // 0..1
    float* Mb = M_all + (size_t)b * (D * D);
    for (int pass = 0; pass < 4; pass++) {
        int jbase = jg * 64 + pass * 16;
        float acc[16];
#pragma unroll
        for (int t = 0; t < 16; t++) acc[t] = 0.f;
        for (int k = 0; k < D; k++) {
            float w = sW[k * D + o];
#pragma unroll
            for (int t = 0; t < 16; t++) acc[t] += sR[jbase + t + k] * w;
        }
#pragma unroll
        for (int t = 0; t < 16; t++) Mb[(size_t)(jbase + t) * D + o] = acc[t];
    }
}

// ---------------- output 1: rel @ w_rel ----------------
__global__ void k_relw(const float* __restrict__ rel, const float* __restrict__ w_rel,
                       float* __restrict__ out2) {
    int rr = blockIdx.x, o = threadIdx.x;
    float acc = 0.f;
    for (int k = 0; k < D; k++) acc += rel[rr * D + k] * w_rel[k * D + o];
    out2[rr * D + o] = acc;
}

// ---------------- edge messages + scatter-add ----------------
// grid = NBUCK * BPB blocks; block stages M[bucket] (64KB) in LDS, streams 16-edge tiles.
constexpr int BPB = 8;
__global__ __launch_bounds__(256) void k_edge(
    const float* __restrict__ x, const float* __restrict__ M_all,
    const int* __restrict__ starts, const int* __restrict__ ssrc,
    const int* __restrict__ sdst, const float* __restrict__ snorm,
    float* __restrict__ out) {
    extern __shared__ float smem[];
    float* sM = smem;                       // 16384 f
    float* sX = smem + D * D;               // 16*128 f
    int*   sDst  = (int*)(smem + D * D + 16 * D);   // 16 i
    float* sNorm = smem + D * D + 16 * D + 16;      // 16 f
    int bucket = blockIdx.x / BPB;
    int bk     = blockIdx.x % BPB;
    int bstart = starts[bucket], bend = starts[bucket + 1];
    const float* Mb = M_all + (size_t)bucket * (D * D);
    for (int i = threadIdx.x * 4; i < D * D; i += blockDim.x * 4)
        *(float4*)&sM[i] = *(const float4*)&Mb[i];
    int o  = threadIdx.x & 127;
    int eg = threadIdx.x >> 7;   // 0..1 -> edges eg*8..eg*8+7
    for (int tbase = bstart + bk * 16; tbase < bend; tbase += BPB * 16) {
        int nv = min(16, bend - tbase);
        __syncthreads();   // previous tile fully consumed (also fences M staging on iter 0)
        for (int q = threadIdx.x; q < 512; q += 256) {   // 16 rows * 32 float4
            int row = q >> 5, c4 = q & 31;
            float4 v = make_float4(0.f, 0.f, 0.f, 0.f);
            if (row < nv) {
                int sr = ssrc[tbase + row];
                v = *(const float4*)&x[(size_t)sr * D + c4 * 4];
            }
            *(float4*)&sX[row * D + c4 * 4] = v;
        }
        if (threadIdx.x < 16) {
            bool ok = threadIdx.x < nv;
            sDst[threadIdx.x]  = ok ? sdst[tbase + threadIdx.x] : -1;
            sNorm[threadIdx.x] = ok ? snorm[tbase + threadIdx.x] : 0.f;
        }
        __syncthreads();
        float acc[8];
#pragma unroll
        for (int t = 0; t < 8; t++) acc[t] = 0.f;
#pragma unroll 2
        for (int j4 = 0; j4 < 32; j4++) {
            float m0 = sM[(j4 * 4 + 0) * D + o];
            float m1 = sM[(j4 * 4 + 1) * D + o];
            float m2 = sM[(j4 * 4 + 2) * D + o];
            float m3 = sM[(j4 * 4 + 3) * D + o];
#pragma unroll
            for (int t = 0; t < 8; t++) {
                float4 xv = *(const float4*)&sX[(eg * 8 + t) * D + j4 * 4];
                acc[t] += xv.x * m0 + xv.y * m1 + xv.z * m2 + xv.w * m3;
            }
        }
#pragma unroll
        for (int t = 0; t < 8; t++) {
            int e = eg * 8 + t;
            int dv = sDst[e];
            if (dv >= 0) atomicAdd(&out[(size_t)dv * D + o], acc[t] * sNorm[e]);
        }
    }
}

// ---------------- self-loop GEMM + (agg+loop)/3 + bias, BN partial sums ----------------
__global__ __launch_bounds__(256) void k_loop(
    const float* __restrict__ x, const float* __restrict__ M_all,
    const float* __restrict__ bias, float* __restrict__ out,
    float* __restrict__ colsum, float* __restrict__ colsq) {
    extern __shared__ float smem[];
    float* sM = smem;
    float* sX = smem + D * D;
    const float* Mb = M_all + (size_t)NBUCK * (D * D);   // Mloop at index 200
    for (int i = threadIdx.x * 4; i < D * D; i += blockDim.x * 4)
        *(float4*)&sM[i] = *(const float4*)&Mb[i];
    int o  = threadIdx.x & 127;
    int eg = threadIdx.x >> 7;
    float bb = bias[o];
    float ps = 0.f, psq = 0.f;
    const int NT = V_N / 16;   // 6250, exact
    for (int tile = blockIdx.x; tile < NT; tile += gridDim.x) {
        int tbase = tile * 16;
        __syncthreads();
        for (int q = threadIdx.x; q < 512; q += 256) {
            int row = q >> 5, c4 = q & 31;
            *(float4*)&sX[row * D + c4 * 4] = *(const float4*)&x[(size_t)(tbase + row) * D + c4 * 4];
        }
        __syncthreads();
        float acc[8];
#pragma unroll
        for (int t = 0; t < 8; t++) acc[t] = 0.f;
#pragma unroll 2
        for (int j4 = 0; j4 < 32; j4++) {
            float m0 = sM[(j4 * 4 + 0) * D + o];
            float m1 = sM[(j4 * 4 + 1) * D + o];
            float m2 = sM[(j4 * 4 + 2) * D + o];
            float m3 = sM[(j4 * 4 + 3) * D + o];
#pragma unroll
            for (int t = 0; t < 8; t++) {
                float4 xv = *(const float4*)&sX[(eg * 8 + t) * D + j4 * 4];
                acc[t] += xv.x * m0 + xv.y * m1 + xv.z * m2 + xv.w * m3;
            }
        }
#pragma unroll
        for (int t = 0; t < 8; t++) {
            int v = tbase + eg * 8 + t;
            size_t idx = (size_t)v * D + o;
            float hv = (out[idx] + acc[t]) * (1.f / 3.f) + bb;
            out[idx] = hv;
            ps += hv; psq += hv * hv;
        }
    }
    atomicAdd(&colsum[o], ps);
    atomicAdd(&colsq[o], psq);
}

// ---------------- BatchNorm normalize in place ----------------
__global__ void k_bn(float* __restrict__ out, const float* __restrict__ colsum,
                     const float* __restrict__ colsq, const float* __restrict__ gamma,
                     const float* __restrict__ beta) {
    const size_t N4 = (size_t)V_N * D / 4;
    size_t stride = (size_t)gridDim.x * blockDim.x;
    for (size_t q = (size_t)blockIdx.x * blockDim.x + threadIdx.x; q < N4; q += stride) {
        int c4 = (int)(q & 31);
        float4 s  = *(const float4*)&colsum[c4 * 4];
        float4 sq = *(const float4*)&colsq[c4 * 4];
        float4 g  = *(const float4*)&gamma[c4 * 4];
        float4 be = *(const float4*)&beta[c4 * 4];
        float4 h  = *(float4*)&out[q * 4];
        const float inv = 1.f / (float)V_N;
        float m0 = s.x * inv, m1 = s.y * inv, m2 = s.z * inv, m3 = s.w * inv;
        float r0 = rsqrtf(sq.x * inv - m0 * m0 + BN_EPS_F);
        float r1 = rsqrtf(sq.y * inv - m1 * m1 + BN_EPS_F);
        float r2 = rsqrtf(sq.z * inv - m2 * m2 + BN_EPS_F);
        float r3 = rsqrtf(sq.w * inv - m3 * m3 + BN_EPS_F);
        h.x = (h.x - m0) * r0 * g.x + be.x;
        h.y = (h.y - m1) * r1 * g.y + be.y;
        h.z = (h.z - m2) * r2 * g.z + be.z;
        h.w = (h.w - m3) * r3 * g.w + be.w;
        *(float4*)&out[q * 4] = h;
    }
}

extern "C" void kernel_launch(void* const* d_in, const int* in_sizes, int n_in,
                              void* d_out, int out_size, void* d_ws, size_t ws_size,
                              hipStream_t stream) {
    const float* x        = (const float*)d_in[0];
    const float* rel      = (const float*)d_in[1];
    const float* enorm    = (const float*)d_in[2];
    const float* in_w     = (const float*)d_in[3];
    const float* out_w    = (const float*)d_in[4];
    const float* loop_w   = (const float*)d_in[5];
    const float* w_rel    = (const float*)d_in[6];
    const float* loop_rel = (const float*)d_in[7];
    const float* bias     = (const float*)d_in[8];
    const float* gamma    = (const float*)d_in[9];
    const float* beta     = (const float*)d_in[10];
    const int*   esrc     = (const int*)d_in[11];
    const int*   edst     = (const int*)d_in[12];
    const int*   etype    = (const int*)d_in[13];
    float* out = (float*)d_out;
    char*  ws  = (char*)d_ws;

    float* M_all  = (float*)(ws + M_OFF);
    int*   ssrc   = (int*)(ws + SS_OFF);
    int*   sdst   = (int*)(ws + SD_OFF);
    float* snorm  = (float*)(ws + SN_OFF);
    int*   counts = (int*)(ws + CNT_OFF);
    float* colsum = (float*)(ws + CS_OFF);
    float* colsq  = (float*)(ws + CQ_OFF);
    int*   starts = (int*)(ws + ST_OFF);
    int*   cursor = (int*)(ws + CUR_OFF);

    // zero the aggregation buffer (output region doubles as agg) + counters
    hipMemsetAsync(out, 0, (size_t)V_N * D * sizeof(float), stream);
    hipMemsetAsync(ws + ZERO_OFF, 0, ZERO_BYTES, stream);

    int gE = (E_N + 255) / 256;
    k_hist<<<gE, 256, 0, stream>>>(etype, counts);
    k_scan<<<1, 64, 0, stream>>>(counts, starts, cursor);
    k_scatter<<<gE, 256, 0, stream>>>(esrc, edst, enorm, etype, cursor, ssrc, sdst, snorm);

    k_build_M<<<201, 256, (D * D + 256) * sizeof(float), stream>>>(
        rel, in_w, out_w, loop_rel, loop_w, M_all);
    k_relw<<<NREL2, D, 0, stream>>>(rel, w_rel, out + (size_t)V_N * D);

    k_edge<<<NBUCK * BPB, 256, (D * D + 16 * D + 32) * sizeof(float), stream>>>(
        x, M_all, starts, ssrc, sdst, snorm, out);

    k_loop<<<512, 256, (D * D + 16 * D) * sizeof(float), stream>>>(
        x, M_all, bias, out, colsum, colsq);

    k_bn<<<2048, 256, 0, stream>>>(out, colsum, colsq, gamma, beta);
}

// Round 2
// 1169.839 us; speedup vs baseline: 1.4225x; 1.4225x over previous
//
#include <hip/hip_runtime.h>
#include <hip/hip_bf16.h>

#define D 128
constexpr int V_N    = 100000;
constexpr int E_N    = 600000;
constexpr int HALF_E = E_N / 2;
constexpr int NREL2  = 100;
constexpr int NBUCK  = 2 * NREL2;   // 200 edge buckets; M index 200 = self-loop
constexpr float BN_EPS_F = 1e-5f;

typedef short bf16x8  __attribute__((ext_vector_type(8)));   // 8 bf16 (4 VGPRs)
typedef float f32x16  __attribute__((ext_vector_type(16)));  // MFMA 32x32 acc
typedef float f32x4v  __attribute__((ext_vector_type(4)));

// ---------------- workspace layout (bytes) — offsets unchanged from R0 ----------------
constexpr size_t M_RSV    = 201ull * D * D * 4;          // region reserved (bf16 M_T uses half)
constexpr size_t M_OFF    = 0;
constexpr size_t SS_OFF   = M_RSV;                       // sorted src (int[E])
constexpr size_t SD_OFF   = SS_OFF + (size_t)E_N * 4;    // sorted dst
constexpr size_t SN_OFF   = SD_OFF + (size_t)E_N * 4;    // sorted norm
constexpr size_t ZERO_OFF = SN_OFF + (size_t)E_N * 4;    // zeroed every launch:
constexpr size_t CNT_OFF  = ZERO_OFF;                    //   counts[200] int (pad to 1024B)
constexpr size_t CS_OFF   = ZERO_OFF + 1024;             //   colsum[128] f32
constexpr size_t CQ_OFF   = CS_OFF + 512;                //   colsq[128] f32
constexpr size_t ZERO_BYTES = 2048;
constexpr size_t ST_OFF   = ZERO_OFF + ZERO_BYTES;       // starts[201] int (written by scan)
constexpr size_t CUR_OFF  = ST_OFF + 1024;               // cursors[200] int

__device__ inline unsigned short f2bf(float f) {
    __hip_bfloat16 h = __float2bfloat16(f);               // RNE
    return __builtin_bit_cast(unsigned short, h);
}

// ---------------- sort: histogram ----------------
__global__ void k_hist(const int* __restrict__ etype, int* __restrict__ counts) {
    __shared__ int h[NBUCK];
    for (int i = threadIdx.x; i < NBUCK; i += blockDim.x) h[i] = 0;
    __syncthreads();
    int e = blockIdx.x * blockDim.x + threadIdx.x;
    if (e < E_N) {
        int b = etype[e] + (e < HALF_E ? 0 : NREL2);
        atomicAdd(&h[b], 1);
    }
    __syncthreads();
    for (int i = threadIdx.x; i < NBUCK; i += blockDim.x)
        if (h[i]) atomicAdd(&counts[i], h[i]);
}

// ---------------- sort: exclusive scan (parallel, 256-wide Hillis-Steele) ----------------
__global__ void k_scan(const int* __restrict__ counts, int* __restrict__ starts,
                       int* __restrict__ cursor) {
    __shared__ int s[256];
    int i = threadIdx.x;
    int v = (i < NBUCK) ? counts[i] : 0;
    s[i] = v;
    __syncthreads();
    for (int off = 1; off < 256; off <<= 1) {
        int t = (i >= off) ? s[i - off] : 0;
        __syncthreads();
        s[i] += t;
        __syncthreads();
    }
    int excl = s[i] - v;
    if (i < NBUCK) { starts[i] = excl; cursor[i] = excl; }
    if (i == 255) starts[NBUCK] = s[255];
}

// ---------------- sort: scatter edge records ----------------
__global__ void k_scatter(const int* __restrict__ src, const int* __restrict__ dst,
                          const float* __restrict__ norm, const int* __restrict__ etype,
                          int* __restrict__ cursor, int* __restrict__ ssrc,
                          int* __restrict__ sdst, float* __restrict__ snorm) {
    int e = blockIdx.x * blockDim.x + threadIdx.x;
    if (e >= E_N) return;
    int b = etype[e] + (e < HALF_E ? 0 : NREL2);
    int p = atomicAdd(&cursor[b], 1);
    ssrc[p] = src[e]; sdst[p] = dst[e]; snorm[p] = norm[e];
}

// ---------------- build transposed bf16 M matrices ----------------
// M[j][o] = sum_k r[(j+k)%128] * W[k][o];  store MT[b][o][j] = bf16(M[j][o])
// blocks 0..99: rel[b], in_w ; 100..199: rel[b-100], out_w ; 200: loop_rel, loop_w
__global__ void k_build_M(const float* __restrict__ rel, const float* __restrict__ in_w,
                          const float* __restrict__ out_w, const float* __restrict__ loop_rel,
                          const float* __restrict__ loop_w, ushort* __restrict__ MT) {
    extern __shared__ float smem[];
    float* sW = smem;            // 128*128
    float* sR = smem + D * D;    // 256 (r duplicated to avoid %128)
    int b = blockIdx.x;
    const float* r = (b < NREL2) ? rel + (size_t)b * D
                   : (b < NBUCK) ? rel + (size_t)(b - NREL2) * D : loop_rel;
    const float* W = (b < NREL2) ? in_w : (b < NBUCK) ? out_w : loop_w;
    for (int i = threadIdx.x; i < D * D; i += blockDim.x) sW[i] = W[i];
    for (int i = threadIdx.x; i < D; i += blockDim.x) { float v = r[i]; sR[i] = v; sR[i + D] = v; }
    __syncthreads();
    int o  = threadIdx.x & 127;
    int jg = threadIdx.x >> 7;   // 0..1
    ushort* MTb = MT + (size_t)b * (D * D);
    for (int pass = 0; pass < 4; pass++) {
        int jbase = jg * 64 + pass * 16;
        float acc[16];
#pragma unroll
        for (int t = 0; t < 16; t++) acc[t] = 0.f;
        for (int k = 0; k < D; k++) {
            float w = sW[k * D + o];
#pragma unroll
            for (int t = 0; t < 16; t++) acc[t] += sR[jbase + t + k] * w;
        }
#pragma unroll
        for (int t = 0; t < 16; t++) MTb[(size_t)o * D + jbase + t] = f2bf(acc[t]);
    }
}

// ---------------- output 1: rel @ w_rel ----------------
__global__ void k_relw(const float* __restrict__ rel, const float* __restrict__ w_rel,
                       float* __restrict__ out2) {
    int rr = blockIdx.x, o = threadIdx.x;
    float acc = 0.f;
    for (int k = 0; k < D; k++) acc += rel[rr * D + k] * w_rel[k * D + o];
    out2[rr * D + o] = acc;
}

// ---------------- edge messages (MFMA) + scatter-add ----------------
// wave = one 32-edge tile stream x 64-out half of one bucket. B persistent in VGPRs.
constexpr int BPB = 8;   // blocks per bucket -> 16 streams/bucket
__global__ __launch_bounds__(256) void k_edge(
    const float* __restrict__ x, const ushort* __restrict__ MT,
    const int* __restrict__ starts, const int* __restrict__ ssrc,
    const int* __restrict__ sdst, const float* __restrict__ snorm,
    float* __restrict__ out) {
    int wid  = threadIdx.x >> 6, lane = threadIdx.x & 63;
    int l31  = lane & 31, l5 = lane >> 5;
    int bucket = blockIdx.x / BPB;
    int sib    = (blockIdx.x % BPB) * 2 + (wid >> 1);   // 0..15
    int oh     = wid & 1;
    int bstart = starts[bucket], bend = starts[bucket + 1];
    const ushort* MTb = MT + (size_t)bucket * (D * D);
    int ocol0 = oh * 64 + l31, ocol1 = oh * 64 + 32 + l31;
    bf16x8 B0[8], B1[8];
#pragma unroll
    for (int kc = 0; kc < 8; kc++) {
        B0[kc] = *(const bf16x8*)&MTb[(size_t)ocol0 * D + kc * 16 + l5 * 8];
        B1[kc] = *(const bf16x8*)&MTb[(size_t)ocol1 * D + kc * 16 + l5 * 8];
    }
    for (int tbase = bstart + sib * 32; tbase < bend; tbase += BPB * 2 * 32) {
        int nv = bend - tbase; if (nv > 32) nv = 32;
        int sr = ssrc[tbase + (l31 < nv ? l31 : 0)];
        const float* xr = x + (size_t)sr * D + l5 * 8;
        bf16x8 A[8];
#pragma unroll
        for (int kc = 0; kc < 8; kc++) {
            f32x4v v0 = *(const f32x4v*)(xr + kc * 16);
            f32x4v v1 = *(const f32x4v*)(xr + kc * 16 + 4);
            union { bf16x8 v; ushort u[8]; } t;
            t.u[0] = f2bf(v0[0]); t.u[1] = f2bf(v0[1]); t.u[2] = f2bf(v0[2]); t.u[3] = f2bf(v0[3]);
            t.u[4] = f2bf(v1[0]); t.u[5] = f2bf(v1[1]); t.u[6] = f2bf(v1[2]); t.u[7] = f2bf(v1[3]);
            A[kc] = t.v;
        }
        f32x16 C0, C1;
#pragma unroll
        for (int i = 0; i < 16; i++) { C0[i] = 0.f; C1[i] = 0.f; }
#pragma unroll
        for (int kc = 0; kc < 8; kc++) {
            C0 = __builtin_amdgcn_mfma_f32_32x32x16_bf16(A[kc], B0[kc], C0, 0, 0, 0);
            C1 = __builtin_amdgcn_mfma_f32_32x32x16_bf16(A[kc], B1[kc], C1, 0, 0, 0);
        }
#pragma unroll
        for (int r = 0; r < 16; r++) {
            int rw = (r & 3) + 8 * (r >> 2) + 4 * l5;
            if (rw < nv) {
                float nm = snorm[tbase + rw];
                int   dv = sdst[tbase + rw];
                float* op = out + (size_t)dv * D;
                atomicAdd(op + ocol0, C0[r] * nm);
                atomicAdd(op + ocol1, C1[r] * nm);
            }
        }
    }
}

// ---------------- self-loop GEMM (MFMA) + (agg+loop)/3 + bias, BN partials ----------------
constexpr int LOOP_GRID = 400;
__global__ __launch_bounds__(256) void k_loop(
    const float* __restrict__ x, const ushort* __restrict__ MT,
    const float* __restrict__ bias, float* __restrict__ out,
    float* __restrict__ colsum, float* __restrict__ colsq) {
    int wid = threadIdx.x >> 6, lane = threadIdx.x & 63;
    int l31 = lane & 31, l5 = lane >> 5;
    int oh  = wid & 1;
    int strm = blockIdx.x * 2 + (wid >> 1);
    const int NSTR = LOOP_GRID * 2;
    const ushort* MTb = MT + (size_t)NBUCK * (D * D);   // Mloop at index 200
    int ocol0 = oh * 64 + l31, ocol1 = oh * 64 + 32 + l31;
    bf16x8 B0[8], B1[8];
#pragma unroll
    for (int kc = 0; kc < 8; kc++) {
        B0[kc] = *(const bf16x8*)&MTb[(size_t)ocol0 * D + kc * 16 + l5 * 8];
        B1[kc] = *(const bf16x8*)&MTb[(size_t)ocol1 * D + kc * 16 + l5 * 8];
    }
    float b0 = bias[ocol0], b1 = bias[ocol1];
    float ps0 = 0.f, pq0 = 0.f, ps1 = 0.f, pq1 = 0.f;
    const int NT = V_N / 32;   // 3125, exact
    for (int tile = strm; tile < NT; tile += NSTR) {
        int tbase = tile * 32;
        const float* xr = x + (size_t)(tbase + l31) * D + l5 * 8;
        bf16x8 A[8];
#pragma unroll
        for (int kc = 0; kc < 8; kc++) {
            f32x4v v0 = *(const f32x4v*)(xr + kc * 16);
            f32x4v v1 = *(const f32x4v*)(xr + kc * 16 + 4);
            union { bf16x8 v; ushort u[8]; } t;
            t.u[0] = f2bf(v0[0]); t.u[1] = f2bf(v0[1]); t.u[2] = f2bf(v0[2]); t.u[3] = f2bf(v0[3]);
            t.u[4] = f2bf(v1[0]); t.u[5] = f2bf(v1[1]); t.u[6] = f2bf(v1[2]); t.u[7] = f2bf(v1[3]);
            A[kc] = t.v;
        }
        f32x16 C0, C1;
#pragma unroll
        for (int i = 0; i < 16; i++) { C0[i] = 0.f; C1[i] = 0.f; }
#pragma unroll
        for (int kc = 0; kc < 8; kc++) {
            C0 = __builtin_amdgcn_mfma_f32_32x32x16_bf16(A[kc], B0[kc], C0, 0, 0, 0);
            C1 = __builtin_amdgcn_mfma_f32_32x32x16_bf16(A[kc], B1[kc], C1, 0, 0, 0);
        }
#pragma unroll
        for (int r = 0; r < 16; r++) {
            int rw = (r & 3) + 8 * (r >> 2) + 4 * l5;
            size_t i0 = (size_t)(tbase + rw) * D + ocol0;
            size_t i1 = (size_t)(tbase + rw) * D + ocol1;
            float h0 = (out[i0] + C0[r]) * (1.f / 3.f) + b0;
            float h1 = (out[i1] + C1[r]) * (1.f / 3.f) + b1;
            out[i0] = h0; out[i1] = h1;
            ps0 += h0; pq0 += h0 * h0;
            ps1 += h1; pq1 += h1 * h1;
        }
    }
    atomicAdd(&colsum[ocol0], ps0); atomicAdd(&colsq[ocol0], pq0);
    atomicAdd(&colsum[ocol1], ps1); atomicAdd(&colsq[ocol1], pq1);
}

// ---------------- BatchNorm normalize in place ----------------
__global__ void k_bn(float* __restrict__ out, const float* __restrict__ colsum,
                     const float* __restrict__ colsq, const float* __restrict__ gamma,
                     const float* __restrict__ beta) {
    const size_t N4 = (size_t)V_N * D / 4;
    size_t stride = (size_t)gridDim.x * blockDim.x;
    for (size_t q = (size_t)blockIdx.x * blockDim.x + threadIdx.x; q < N4; q += stride) {
        int c4 = (int)(q & 31);
        float4 s  = *(const float4*)&colsum[c4 * 4];
        float4 sq = *(const float4*)&colsq[c4 * 4];
        float4 g  = *(const float4*)&gamma[c4 * 4];
        float4 be = *(const float4*)&beta[c4 * 4];
        float4 h  = *(float4*)&out[q * 4];
        const float inv = 1.f / (float)V_N;
        float m0 = s.x * inv, m1 = s.y * inv, m2 = s.z * inv, m3 = s.w * inv;
        float r0 = rsqrtf(sq.x * inv - m0 * m0 + BN_EPS_F);
        float r1 = rsqrtf(sq.y * inv - m1 * m1 + BN_EPS_F);
        float r2 = rsqrtf(sq.z * inv - m2 * m2 + BN_EPS_F);
        float r3 = rsqrtf(sq.w * inv - m3 * m3 + BN_EPS_F);
        h.x = (h.x - m0) * r0 * g.x + be.x;
        h.y = (h.y - m1) * r1 * g.y + be.y;
        h.z = (h.z - m2) * r2 * g.z + be.z;
        h.w = (h.w - m3) * r3 * g.w + be.w;
        *(float4*)&out[q * 4] = h;
    }
}

extern "C" void kernel_launch(void* const* d_in, const int* in_sizes, int n_in,
                              void* d_out, int out_size, void* d_ws, size_t ws_size,
                              hipStream_t stream) {
    const float* x        = (const float*)d_in[0];
    const float* rel      = (const float*)d_in[1];
    const float* enorm    = (const float*)d_in[2];
    const float* in_w     = (const float*)d_in[3];
    const float* out_w    = (const float*)d_in[4];
    const float* loop_w   = (const float*)d_in[5];
    const float* w_rel    = (const float*)d_in[6];
    const float* loop_rel = (const float*)d_in[7];
    const float* bias     = (const float*)d_in[8];
    const float* gamma    = (const float*)d_in[9];
    const float* beta     = (const float*)d_in[10];
    const int*   esrc     = (const int*)d_in[11];
    const int*   edst     = (const int*)d_in[12];
    const int*   etype    = (const int*)d_in[13];
    float* out = (float*)d_out;
    char*  ws  = (char*)d_ws;

    ushort* MT    = (ushort*)(ws + M_OFF);
    int*   ssrc   = (int*)(ws + SS_OFF);
    int*   sdst   = (int*)(ws + SD_OFF);
    float* snorm  = (float*)(ws + SN_OFF);
    int*   counts = (int*)(ws + CNT_OFF);
    float* colsum = (float*)(ws + CS_OFF);
    float* colsq  = (float*)(ws + CQ_OFF);
    int*   starts = (int*)(ws + ST_OFF);
    int*   cursor = (int*)(ws + CUR_OFF);

    // zero the aggregation buffer (output region doubles as agg) + counters
    hipMemsetAsync(out, 0, (size_t)V_N * D * sizeof(float), stream);
    hipMemsetAsync(ws + ZERO_OFF, 0, ZERO_BYTES, stream);

    int gE = (E_N + 255) / 256;
    k_hist<<<gE, 256, 0, stream>>>(etype, counts);
    k_scan<<<1, 256, 0, stream>>>(counts, starts, cursor);
    k_scatter<<<gE, 256, 0, stream>>>(esrc, edst, enorm, etype, cursor, ssrc, sdst, snorm);

    k_build_M<<<201, 256, (D * D + 256) * sizeof(float), stream>>>(
        rel, in_w, out_w, loop_rel, loop_w, MT);
    k_relw<<<NREL2, D, 0, stream>>>(rel, w_rel, out + (size_t)V_N * D);

    k_edge<<<NBUCK * BPB, 256, 0, stream>>>(x, MT, starts, ssrc, sdst, snorm, out);

    k_loop<<<LOOP_GRID, 256, 0, stream>>>(x, MT, bias, out, colsum, colsq);

    k_bn<<<2048, 256, 0, stream>>>(out, colsum, colsq, gamma, beta);
}

// Round 5
// 675.732 us; speedup vs baseline: 2.4627x; 1.7312x over previous
//
#include <hip/hip_runtime.h>
#include <hip/hip_bf16.h>

#define D 128
constexpr int V_N    = 100000;
constexpr int E_N    = 600000;
constexpr int HALF_E = E_N / 2;
constexpr int NREL2  = 100;
constexpr int NBUCK  = 2 * NREL2;   // 200 edge buckets; M index 200 = self-loop
constexpr float BN_EPS_F = 1e-5f;

constexpr int CHUNK  = 4096;
constexpr int NCHUNK = (E_N + CHUNK - 1) / CHUNK;   // 147

typedef short bf16x8  __attribute__((ext_vector_type(8)));   // 8 bf16 (4 VGPRs)
typedef float f32x16  __attribute__((ext_vector_type(16)));  // MFMA 32x32 acc
typedef float f32x4v  __attribute__((ext_vector_type(4)));

// ---------------- workspace layout (bytes) ----------------
constexpr size_t M_RSV    = 201ull * D * D * 4;          // fp32-sized reservation
constexpr size_t M_OFF    = 0;                           // MT (bf16) uses first half
constexpr size_t HIST_OFF = 201ull * D * D * 2;          // hist[NBUCK][NCHUNK] int
constexpr size_t COFF_OFF = HIST_OFF + (size_t)NBUCK * NCHUNK * 4;  // chunkoff, same shape
// (HIST/COFF end ~6.82 MB < M_RSV 13.17 MB)
constexpr size_t SS_OFF   = M_RSV;                       // sorted src (int[E])
constexpr size_t SD_OFF   = SS_OFF + (size_t)E_N * 4;    // sorted dst
constexpr size_t SN_OFF   = SD_OFF + (size_t)E_N * 4;    // sorted norm
constexpr size_t ZERO_OFF = SN_OFF + (size_t)E_N * 4;    // zeroed every launch:
constexpr size_t CNT_OFF  = ZERO_OFF;                    //   counts[200] int
constexpr size_t CS_OFF   = ZERO_OFF + 1024;             //   colsum[128] f32
constexpr size_t CQ_OFF   = CS_OFF + 512;                //   colsq[128] f32
constexpr size_t ZERO_BYTES = 2048;
constexpr size_t ST_OFF   = ZERO_OFF + ZERO_BYTES;       // starts[201] int

__device__ inline unsigned short f2bf(float f) {
    __hip_bfloat16 h = __float2bfloat16(f);               // RNE
    return __builtin_bit_cast(unsigned short, h);
}

__device__ inline int bucket_of(int e, const int* __restrict__ etype) {
    return etype[e] + (e < HALF_E ? 0 : NREL2);
}

// ---------------- sort phase 1: per-chunk histogram (LDS only) ----------------
__global__ __launch_bounds__(256) void k_hist_chunk(const int* __restrict__ etype,
                                                    int* __restrict__ hist) {
    __shared__ int h[NBUCK];
    for (int i = threadIdx.x; i < NBUCK; i += 256) h[i] = 0;
    __syncthreads();
    int c = blockIdx.x;
    int e0 = c * CHUNK;
#pragma unroll
    for (int r = 0; r < CHUNK / 256; r++) {
        int e = e0 + r * 256 + threadIdx.x;
        if (e < E_N) atomicAdd(&h[bucket_of(e, etype)], 1);
    }
    __syncthreads();
    for (int b = threadIdx.x; b < NBUCK; b += 256) hist[b * NCHUNK + c] = h[b];
}

// ---------------- sort phase 2: per-bucket scan over chunks (1 wave/bucket) ----------------
__global__ void k_scan_bucket(const int* __restrict__ hist, int* __restrict__ chunkoff,
                              int* __restrict__ counts) {
    int b = blockIdx.x, lane = threadIdx.x;   // 64 lanes
    int acc = 0;
    for (int base = 0; base < NCHUNK; base += 64) {
        int c = base + lane;
        int v = (c < NCHUNK) ? hist[b * NCHUNK + c] : 0;
        int s = v;
#pragma unroll
        for (int off = 1; off < 64; off <<= 1) {
            int t = __shfl(s, lane - off, 64);
            if (lane >= off) s += t;
        }
        if (c < NCHUNK) chunkoff[b * NCHUNK + c] = acc + (s - v);
        acc += __shfl(s, 63, 64);
    }
    if (lane == 0) counts[b] = acc;
}

// ---------------- sort phase 3: bucket starts (200-wide Hillis-Steele) ----------------
__global__ void k_scan(const int* __restrict__ counts, int* __restrict__ starts) {
    __shared__ int s[256];
    int i = threadIdx.x;
    int v = (i < NBUCK) ? counts[i] : 0;
    s[i] = v;
    __syncthreads();
    for (int off = 1; off < 256; off <<= 1) {
        int t = (i >= off) ? s[i - off] : 0;
        __syncthreads();
        s[i] += t;
        __syncthreads();
    }
    if (i < NBUCK) starts[i] = s[i] - v;
    if (i == 255) starts[NBUCK] = s[255];
}

// ---------------- sort phase 4: scatter with LDS ranks (no global atomics) ----------------
__global__ __launch_bounds__(256) void k_scatter2(
    const int* __restrict__ src, const int* __restrict__ dst,
    const float* __restrict__ norm, const int* __restrict__ etype,
    const int* __restrict__ starts, const int* __restrict__ chunkoff,
    int* __restrict__ ssrc, int* __restrict__ sdst, float* __restrict__ snorm) {
    __shared__ int h[NBUCK];
    __shared__ int sbase[NBUCK];
    int c = blockIdx.x;
    for (int b = threadIdx.x; b < NBUCK; b += 256) {
        h[b] = 0;
        sbase[b] = starts[b] + chunkoff[b * NCHUNK + c];
    }
    __syncthreads();
    int e0 = c * CHUNK;
#pragma unroll
    for (int r = 0; r < CHUNK / 256; r++) {
        int e = e0 + r * 256 + threadIdx.x;
        if (e < E_N) {
            int b = bucket_of(e, etype);
            int rank = atomicAdd(&h[b], 1);
            int p = sbase[b] + rank;
            ssrc[p] = src[e]; sdst[p] = dst[e]; snorm[p] = norm[e];
        }
    }
}

// ---------------- build transposed bf16 M matrices ----------------
// M[j][o] = sum_k r[(j+k)%128] * W[k][o];  store MT[b][o][j] = bf16(M[j][o])
__global__ void k_build_M(const float* __restrict__ rel, const float* __restrict__ in_w,
                          const float* __restrict__ out_w, const float* __restrict__ loop_rel,
                          const float* __restrict__ loop_w, ushort* __restrict__ MT) {
    extern __shared__ float smem[];
    float* sW = smem;            // 128*128
    float* sR = smem + D * D;    // 256 (r duplicated to avoid %128)
    int b = blockIdx.x;
    const float* r = (b < NREL2) ? rel + (size_t)b * D
                   : (b < NBUCK) ? rel + (size_t)(b - NREL2) * D : loop_rel;
    const float* W = (b < NREL2) ? in_w : (b < NBUCK) ? out_w : loop_w;
    for (int i = threadIdx.x; i < D * D; i += blockDim.x) sW[i] = W[i];
    for (int i = threadIdx.x; i < D; i += blockDim.x) { float v = r[i]; sR[i] = v; sR[i + D] = v; }
    __syncthreads();
    int o  = threadIdx.x & 127;
    int jg = threadIdx.x >> 7;   // 0..1
    ushort* MTb = MT + (size_t)b * (D * D);
    for (int pass = 0; pass < 4; pass++) {
        int jbase = jg * 64 + pass * 16;
        float acc[16];
#pragma unroll
        for (int t = 0; t < 16; t++) acc[t] = 0.f;
        for (int k = 0; k < D; k++) {
            float w = sW[k * D + o];
#pragma unroll
            for (int t = 0; t < 16; t++) acc[t] += sR[jbase + t + k] * w;
        }
#pragma unroll
        for (int t = 0; t < 16; t++) MTb[(size_t)o * D + jbase + t] = f2bf(acc[t]);
    }
}

// ---------------- output 1: rel @ w_rel ----------------
__global__ void k_relw(const float* __restrict__ rel, const float* __restrict__ w_rel,
                       float* __restrict__ out2) {
    int rr = blockIdx.x, o = threadIdx.x;
    float acc = 0.f;
    for (int k = 0; k < D; k++) acc += rel[rr * D + k] * w_rel[k * D + o];
    out2[rr * D + o] = acc;
}

// ---------------- edge messages (MFMA) + scatter-add ----------------
// wave = one 32-edge tile stream x 64-out half of one bucket. B persistent in VGPRs.
constexpr int BPB = 8;   // blocks per bucket -> 16 streams/bucket
__global__ __launch_bounds__(256) void k_edge(
    const float* __restrict__ x, const ushort* __restrict__ MT,
    const int* __restrict__ starts, const int* __restrict__ ssrc,
    const int* __restrict__ sdst, const float* __restrict__ snorm,
    float* __restrict__ out) {
    int wid  = threadIdx.x >> 6, lane = threadIdx.x & 63;
    int l31  = lane & 31, l5 = lane >> 5;
    int bucket = blockIdx.x / BPB;
    int sib    = (blockIdx.x % BPB) * 2 + (wid >> 1);   // 0..15
    int oh     = wid & 1;
    int bstart = starts[bucket], bend = starts[bucket + 1];
    const ushort* MTb = MT + (size_t)bucket * (D * D);
    int ocol0 = oh * 64 + l31, ocol1 = oh * 64 + 32 + l31;
    bf16x8 B0[8], B1[8];
#pragma unroll
    for (int kc = 0; kc < 8; kc++) {
        B0[kc] = *(const bf16x8*)&MTb[(size_t)ocol0 * D + kc * 16 + l5 * 8];
        B1[kc] = *(const bf16x8*)&MTb[(size_t)ocol1 * D + kc * 16 + l5 * 8];
    }
    for (int tbase = bstart + sib * 32; tbase < bend; tbase += BPB * 2 * 32) {
        int nv = bend - tbase; if (nv > 32) nv = 32;
        int sr = ssrc[tbase + (l31 < nv ? l31 : 0)];
        const float* xr = x + (size_t)sr * D + l5 * 8;
        bf16x8 A[8];
#pragma unroll
        for (int kc = 0; kc < 8; kc++) {
            f32x4v v0 = *(const f32x4v*)(xr + kc * 16);
            f32x4v v1 = *(const f32x4v*)(xr + kc * 16 + 4);
            union { bf16x8 v; ushort u[8]; } t;
            t.u[0] = f2bf(v0[0]); t.u[1] = f2bf(v0[1]); t.u[2] = f2bf(v0[2]); t.u[3] = f2bf(v0[3]);
            t.u[4] = f2bf(v1[0]); t.u[5] = f2bf(v1[1]); t.u[6] = f2bf(v1[2]); t.u[7] = f2bf(v1[3]);
            A[kc] = t.v;
        }
        f32x16 C0, C1;
#pragma unroll
        for (int i = 0; i < 16; i++) { C0[i] = 0.f; C1[i] = 0.f; }
#pragma unroll
        for (int kc = 0; kc < 8; kc++) {
            C0 = __builtin_amdgcn_mfma_f32_32x32x16_bf16(A[kc], B0[kc], C0, 0, 0, 0);
            C1 = __builtin_amdgcn_mfma_f32_32x32x16_bf16(A[kc], B1[kc], C1, 0, 0, 0);
        }
#pragma unroll
        for (int r = 0; r < 16; r++) {
            int rw = (r & 3) + 8 * (r >> 2) + 4 * l5;
            if (rw < nv) {
                float nm = snorm[tbase + rw];
                int   dv = sdst[tbase + rw];
                float* op = out + (size_t)dv * D;
                atomicAdd(op + ocol0, C0[r] * nm);
                atomicAdd(op + ocol1, C1[r] * nm);
            }
        }
    }
}

// ---------------- self-loop GEMM (MFMA) + (agg+loop)/3 + bias, BN partials ----------------
constexpr int LOOP_GRID = 400;
__global__ __launch_bounds__(256) void k_loop(
    const float* __restrict__ x, const ushort* __restrict__ MT,
    const float* __restrict__ bias, float* __restrict__ out,
    float* __restrict__ colsum, float* __restrict__ colsq) {
    int wid = threadIdx.x >> 6, lane = threadIdx.x & 63;
    int l31 = lane & 31, l5 = lane >> 5;
    int oh  = wid & 1;
    int strm = blockIdx.x * 2 + (wid >> 1);
    const int NSTR = LOOP_GRID * 2;
    const ushort* MTb = MT + (size_t)NBUCK * (D * D);   // Mloop at index 200
    int ocol0 = oh * 64 + l31, ocol1 = oh * 64 + 32 + l31;
    bf16x8 B0[8], B1[8];
#pragma unroll
    for (int kc = 0; kc < 8; kc++) {
        B0[kc] = *(const bf16x8*)&MTb[(size_t)ocol0 * D + kc * 16 + l5 * 8];
        B1[kc] = *(const bf16x8*)&MTb[(size_t)ocol1 * D + kc * 16 + l5 * 8];
    }
    float b0 = bias[ocol0], b1 = bias[ocol1];
    float ps0 = 0.f, pq0 = 0.f, ps1 = 0.f, pq1 = 0.f;
    const int NT = V_N / 32;   // 3125, exact
    for (int tile = strm; tile < NT; tile += NSTR) {
        int tbase = tile * 32;
        const float* xr = x + (size_t)(tbase + l31) * D + l5 * 8;
        bf16x8 A[8];
#pragma unroll
        for (int kc = 0; kc < 8; kc++) {
            f32x4v v0 = *(const f32x4v*)(xr + kc * 16);
            f32x4v v1 = *(const f32x4v*)(xr + kc * 16 + 4);
            union { bf16x8 v; ushort u[8]; } t;
            t.u[0] = f2bf(v0[0]); t.u[1] = f2bf(v0[1]); t.u[2] = f2bf(v0[2]); t.u[3] = f2bf(v0[3]);
            t.u[4] = f2bf(v1[0]); t.u[5] = f2bf(v1[1]); t.u[6] = f2bf(v1[2]); t.u[7] = f2bf(v1[3]);
            A[kc] = t.v;
        }
        f32x16 C0, C1;
#pragma unroll
        for (int i = 0; i < 16; i++) { C0[i] = 0.f; C1[i] = 0.f; }
#pragma unroll
        for (int kc = 0; kc < 8; kc++) {
            C0 = __builtin_amdgcn_mfma_f32_32x32x16_bf16(A[kc], B0[kc], C0, 0, 0, 0);
            C1 = __builtin_amdgcn_mfma_f32_32x32x16_bf16(A[kc], B1[kc], C1, 0, 0, 0);
        }
#pragma unroll
        for (int r = 0; r < 16; r++) {
            int rw = (r & 3) + 8 * (r >> 2) + 4 * l5;
            size_t i0 = (size_t)(tbase + rw) * D + ocol0;
            size_t i1 = (size_t)(tbase + rw) * D + ocol1;
            float h0 = (out[i0] + C0[r]) * (1.f / 3.f) + b0;
            float h1 = (out[i1] + C1[r]) * (1.f / 3.f) + b1;
            out[i0] = h0; out[i1] = h1;
            ps0 += h0; pq0 += h0 * h0;
            ps1 += h1; pq1 += h1 * h1;
        }
    }
    atomicAdd(&colsum[ocol0], ps0); atomicAdd(&colsq[ocol0], pq0);
    atomicAdd(&colsum[ocol1], ps1); atomicAdd(&colsq[ocol1], pq1);
}

// ---------------- BatchNorm normalize in place ----------------
__global__ void k_bn(float* __restrict__ out, const float* __restrict__ colsum,
                     const float* __restrict__ colsq, const float* __restrict__ gamma,
                     const float* __restrict__ beta) {
    const size_t N4 = (size_t)V_N * D / 4;
    size_t stride = (size_t)gridDim.x * blockDim.x;
    for (size_t q = (size_t)blockIdx.x * blockDim.x + threadIdx.x; q < N4; q += stride) {
        int c4 = (int)(q & 31);
        float4 s  = *(const float4*)&colsum[c4 * 4];
        float4 sq = *(const float4*)&colsq[c4 * 4];
        float4 g  = *(const float4*)&gamma[c4 * 4];
        float4 be = *(const float4*)&beta[c4 * 4];
        float4 h  = *(float4*)&out[q * 4];
        const float inv = 1.f / (float)V_N;
        float m0 = s.x * inv, m1 = s.y * inv, m2 = s.z * inv, m3 = s.w * inv;
        float r0 = rsqrtf(sq.x * inv - m0 * m0 + BN_EPS_F);
        float r1 = rsqrtf(sq.y * inv - m1 * m1 + BN_EPS_F);
        float r2 = rsqrtf(sq.z * inv - m2 * m2 + BN_EPS_F);
        float r3 = rsqrtf(sq.w * inv - m3 * m3 + BN_EPS_F);
        h.x = (h.x - m0) * r0 * g.x + be.x;
        h.y = (h.y - m1) * r1 * g.y + be.y;
        h.z = (h.z - m2) * r2 * g.z + be.z;
        h.w = (h.w - m3) * r3 * g.w + be.w;
        *(float4*)&out[q * 4] = h;
    }
}

extern "C" void kernel_launch(void* const* d_in, const int* in_sizes, int n_in,
                              void* d_out, int out_size, void* d_ws, size_t ws_size,
                              hipStream_t stream) {
    const float* x        = (const float*)d_in[0];
    const float* rel      = (const float*)d_in[1];
    const float* enorm    = (const float*)d_in[2];
    const float* in_w     = (const float*)d_in[3];
    const float* out_w    = (const float*)d_in[4];
    const float* loop_w   = (const float*)d_in[5];
    const float* w_rel    = (const float*)d_in[6];
    const float* loop_rel = (const float*)d_in[7];
    const float* bias     = (const float*)d_in[8];
    const float* gamma    = (const float*)d_in[9];
    const float* beta     = (const float*)d_in[10];
    const int*   esrc     = (const int*)d_in[11];
    const int*   edst     = (const int*)d_in[12];
    const int*   etype    = (const int*)d_in[13];
    float* out = (float*)d_out;
    char*  ws  = (char*)d_ws;

    ushort* MT      = (ushort*)(ws + M_OFF);
    int*   hist     = (int*)(ws + HIST_OFF);
    int*   chunkoff = (int*)(ws + COFF_OFF);
    int*   ssrc     = (int*)(ws + SS_OFF);
    int*   sdst     = (int*)(ws + SD_OFF);
    float* snorm    = (float*)(ws + SN_OFF);
    int*   counts   = (int*)(ws + CNT_OFF);
    float* colsum   = (float*)(ws + CS_OFF);
    float* colsq    = (float*)(ws + CQ_OFF);
    int*   starts   = (int*)(ws + ST_OFF);

    // zero the aggregation buffer (output region doubles as agg) + BN partials
    hipMemsetAsync(out, 0, (size_t)V_N * D * sizeof(float), stream);
    hipMemsetAsync(ws + ZERO_OFF, 0, ZERO_BYTES, stream);

    // deterministic contention-free counting sort
    k_hist_chunk<<<NCHUNK, 256, 0, stream>>>(etype, hist);
    k_scan_bucket<<<NBUCK, 64, 0, stream>>>(hist, chunkoff, counts);
    k_scan<<<1, 256, 0, stream>>>(counts, starts);
    k_scatter2<<<NCHUNK, 256, 0, stream>>>(esrc, edst, enorm, etype, starts, chunkoff,
                                           ssrc, sdst, snorm);

    k_build_M<<<201, 256, (D * D + 256) * sizeof(float), stream>>>(
        rel, in_w, out_w, loop_rel, loop_w, MT);
    k_relw<<<NREL2, D, 0, stream>>>(rel, w_rel, out + (size_t)V_N * D);

    k_edge<<<NBUCK * BPB, 256, 0, stream>>>(x, MT, starts, ssrc, sdst, snorm, out);

    k_loop<<<LOOP_GRID, 256, 0, stream>>>(x, MT, bias, out, colsum, colsq);

    k_bn<<<2048, 256, 0, stream>>>(out, colsum, colsq, gamma, beta);
}

// Round 7
// 562.325 us; speedup vs baseline: 2.9593x; 1.2017x over previous
//
#include <hip/hip_runtime.h>
#include <hip/hip_bf16.h>

#define D 128
constexpr int V_N    = 100000;
constexpr int E_N    = 600000;
constexpr int HALF_E = E_N / 2;
constexpr int NREL2  = 100;
constexpr int NBUCK  = 2 * NREL2;   // 200 edge buckets; M index 200 = self-loop
constexpr float BN_EPS_F = 1e-5f;

constexpr int CHUNK  = 4096;
constexpr int NCHUNK = (E_N + CHUNK - 1) / CHUNK;   // 147

typedef short bf16x8  __attribute__((ext_vector_type(8)));   // 8 bf16 (4 VGPRs)
typedef float f32x16  __attribute__((ext_vector_type(16)));  // MFMA 32x32 acc
typedef float f32x4v  __attribute__((ext_vector_type(4)));

// ================= legacy (R5) workspace layout =================
constexpr size_t M_RSV    = 201ull * D * D * 4;
constexpr size_t M_OFF    = 0;
constexpr size_t HIST_OFF = 201ull * D * D * 2;
constexpr size_t COFF_OFF = HIST_OFF + (size_t)NBUCK * NCHUNK * 4;
constexpr size_t SS_OFF   = M_RSV;
constexpr size_t SD_OFF   = SS_OFF + (size_t)E_N * 4;
constexpr size_t SN_OFF   = SD_OFF + (size_t)E_N * 4;
constexpr size_t ZERO_OFF = SN_OFF + (size_t)E_N * 4;
constexpr size_t CNT_OFF  = ZERO_OFF;
constexpr size_t CS_OFF   = ZERO_OFF + 1024;
constexpr size_t CQ_OFF   = CS_OFF + 512;
constexpr size_t ZERO_BYTES = 2048;
constexpr size_t ST_OFF   = ZERO_OFF + ZERO_BYTES;

// ================= pk-bf16 workspace layout =================
constexpr size_t MT_BYTES  = 201ull * D * D * 2;             // 6,586,368
constexpr size_t P_SS_OFF  = MT_BYTES;
constexpr size_t P_SD_OFF  = P_SS_OFF + (size_t)E_N * 4;
constexpr size_t P_SN_OFF  = P_SD_OFF + (size_t)E_N * 4;
constexpr size_t P_AGG_OFF = P_SN_OFF + (size_t)E_N * 4;     // bf16[V][D]
constexpr size_t AGG_BYTES = (size_t)V_N * D * 2;            // 25.6 MB
constexpr size_t P_HIST_OFF = P_AGG_OFF;                     // overlay (dead after sort)
constexpr size_t P_COFF_OFF = P_HIST_OFF + (size_t)NBUCK * NCHUNK * 4;
constexpr size_t P_CS_OFF  = P_AGG_OFF + AGG_BYTES;          // colsum 512B (zeroed)
constexpr size_t P_CQ_OFF  = P_CS_OFF + 512;                 // colsq 512B (zeroed)
constexpr size_t P_CNT_OFF = P_CQ_OFF + 512;                 // counts (fully written)
constexpr size_t P_ST_OFF  = P_CNT_OFF + 1024;               // starts (fully written)
constexpr size_t WS_NEED_PK = P_ST_OFF + 1024;               // ~39.4 MB

__device__ inline unsigned short f2bf(float f) {
    __hip_bfloat16 h = __float2bfloat16(f);               // RNE
    return __builtin_bit_cast(unsigned short, h);
}
__device__ inline float bf2f(unsigned short u) {
    return __uint_as_float(((unsigned)u) << 16);
}

__device__ inline int bucket_of(int e, const int* __restrict__ etype) {
    return etype[e] + (e < HALF_E ? 0 : NREL2);
}

// ---------------- sort phase 1: per-chunk histogram (LDS only) ----------------
__global__ __launch_bounds__(256) void k_hist_chunk(const int* __restrict__ etype,
                                                    int* __restrict__ hist) {
    __shared__ int h[NBUCK];
    for (int i = threadIdx.x; i < NBUCK; i += 256) h[i] = 0;
    __syncthreads();
    int c = blockIdx.x;
    int e0 = c * CHUNK;
#pragma unroll
    for (int r = 0; r < CHUNK / 256; r++) {
        int e = e0 + r * 256 + threadIdx.x;
        if (e < E_N) atomicAdd(&h[bucket_of(e, etype)], 1);
    }
    __syncthreads();
    for (int b = threadIdx.x; b < NBUCK; b += 256) hist[b * NCHUNK + c] = h[b];
}

// ---------------- sort phase 2: per-bucket scan over chunks (1 wave/bucket) ----------------
__global__ void k_scan_bucket(const int* __restrict__ hist, int* __restrict__ chunkoff,
                              int* __restrict__ counts) {
    int b = blockIdx.x, lane = threadIdx.x;   // 64 lanes
    int acc = 0;
    for (int base = 0; base < NCHUNK; base += 64) {
        int c = base + lane;
        int v = (c < NCHUNK) ? hist[b * NCHUNK + c] : 0;
        int s = v;
#pragma unroll
        for (int off = 1; off < 64; off <<= 1) {
            int t = __shfl(s, lane - off, 64);
            if (lane >= off) s += t;
        }
        if (c < NCHUNK) chunkoff[b * NCHUNK + c] = acc + (s - v);
        acc += __shfl(s, 63, 64);
    }
    if (lane == 0) counts[b] = acc;
}

// ---------------- sort phase 3: bucket starts (200-wide Hillis-Steele) ----------------
__global__ void k_scan(const int* __restrict__ counts, int* __restrict__ starts) {
    __shared__ int s[256];
    int i = threadIdx.x;
    int v = (i < NBUCK) ? counts[i] : 0;
    s[i] = v;
    __syncthreads();
    for (int off = 1; off < 256; off <<= 1) {
        int t = (i >= off) ? s[i - off] : 0;
        __syncthreads();
        s[i] += t;
        __syncthreads();
    }
    if (i < NBUCK) starts[i] = s[i] - v;
    if (i == 255) starts[NBUCK] = s[255];
}

// ---------------- sort phase 4: scatter with LDS ranks (no global atomics) ----------------
__global__ __launch_bounds__(256) void k_scatter2(
    const int* __restrict__ src, const int* __restrict__ dst,
    const float* __restrict__ norm, const int* __restrict__ etype,
    const int* __restrict__ starts, const int* __restrict__ chunkoff,
    int* __restrict__ ssrc, int* __restrict__ sdst, float* __restrict__ snorm) {
    __shared__ int h[NBUCK];
    __shared__ int sbase[NBUCK];
    int c = blockIdx.x;
    for (int b = threadIdx.x; b < NBUCK; b += 256) {
        h[b] = 0;
        sbase[b] = starts[b] + chunkoff[b * NCHUNK + c];
    }
    __syncthreads();
    int e0 = c * CHUNK;
#pragma unroll
    for (int r = 0; r < CHUNK / 256; r++) {
        int e = e0 + r * 256 + threadIdx.x;
        if (e < E_N) {
            int b = bucket_of(e, etype);
            int rank = atomicAdd(&h[b], 1);
            int p = sbase[b] + rank;
            ssrc[p] = src[e]; sdst[p] = dst[e]; snorm[p] = norm[e];
        }
    }
}

// ---------------- build transposed bf16 M matrices ----------------
// M[j][o] = sum_k r[(j+k)%128] * W[k][o];  store MT[b][o][j] = bf16(M[j][o])
__global__ void k_build_M(const float* __restrict__ rel, const float* __restrict__ in_w,
                          const float* __restrict__ out_w, const float* __restrict__ loop_rel,
                          const float* __restrict__ loop_w, ushort* __restrict__ MT) {
    extern __shared__ float smem[];
    float* sW = smem;            // 128*128
    float* sR = smem + D * D;    // 256 (r duplicated to avoid %128)
    int b = blockIdx.x;
    const float* r = (b < NREL2) ? rel + (size_t)b * D
                   : (b < NBUCK) ? rel + (size_t)(b - NREL2) * D : loop_rel;
    const float* W = (b < NREL2) ? in_w : (b < NBUCK) ? out_w : loop_w;
    for (int i = threadIdx.x; i < D * D; i += blockDim.x) sW[i] = W[i];
    for (int i = threadIdx.x; i < D; i += blockDim.x) { float v = r[i]; sR[i] = v; sR[i + D] = v; }
    __syncthreads();
    int o  = threadIdx.x & 127;
    int jg = threadIdx.x >> 7;   // 0..1
    ushort* MTb = MT + (size_t)b * (D * D);
    for (int pass = 0; pass < 4; pass++) {
        int jbase = jg * 64 + pass * 16;
        float acc[16];
#pragma unroll
        for (int t = 0; t < 16; t++) acc[t] = 0.f;
        for (int k = 0; k < D; k++) {
            float w = sW[k * D + o];
#pragma unroll
            for (int t = 0; t < 16; t++) acc[t] += sR[jbase + t + k] * w;
        }
#pragma unroll
        for (int t = 0; t < 16; t++) MTb[(size_t)o * D + jbase + t] = f2bf(acc[t]);
    }
}

// ---------------- output 1: rel @ w_rel ----------------
__global__ void k_relw(const float* __restrict__ rel, const float* __restrict__ w_rel,
                       float* __restrict__ out2) {
    int rr = blockIdx.x, o = threadIdx.x;
    float acc = 0.f;
    for (int k = 0; k < D; k++) acc += rel[rr * D + k] * w_rel[k * D + o];
    out2[rr * D + o] = acc;
}

constexpr int BPB = 8;   // blocks per bucket -> 16 streams/bucket

// ---------------- edge messages (MFMA) + packed bf16 atomic scatter ----------------
// B-fragment columns permuted to even/odd pairs so lane l holds adjacent output
// cols (2*l31, 2*l31+1) -> one global_atomic_pk_add_bf16 per (row, col-pair).
__global__ __launch_bounds__(256) void k_edge_pk(
    const float* __restrict__ x, const ushort* __restrict__ MT,
    const int* __restrict__ starts, const int* __restrict__ ssrc,
    const int* __restrict__ sdst, const float* __restrict__ snorm,
    ushort* __restrict__ agg) {
    int wid  = threadIdx.x >> 6, lane = threadIdx.x & 63;
    int l31  = lane & 31, l5 = lane >> 5;
    int bucket = blockIdx.x / BPB;
    int sib    = (blockIdx.x % BPB) * 2 + (wid >> 1);   // 0..15
    int oh     = wid & 1;
    int bstart = starts[bucket], bend = starts[bucket + 1];
    const ushort* MTb = MT + (size_t)bucket * (D * D);
    int c0 = oh * 64 + 2 * l31;          // even col; odd partner is c0+1
    bf16x8 B0[8], B1[8];
#pragma unroll
    for (int kc = 0; kc < 8; kc++) {
        B0[kc] = *(const bf16x8*)&MTb[(size_t)c0 * D + kc * 16 + l5 * 8];
        B1[kc] = *(const bf16x8*)&MTb[(size_t)(c0 + 1) * D + kc * 16 + l5 * 8];
    }
    for (int tbase = bstart + sib * 32; tbase < bend; tbase += BPB * 2 * 32) {
        int nv = bend - tbase; if (nv > 32) nv = 32;
        int sr = ssrc[tbase + (l31 < nv ? l31 : 0)];
        const float* xr = x + (size_t)sr * D + l5 * 8;
        bf16x8 A[8];
#pragma unroll
        for (int kc = 0; kc < 8; kc++) {
            f32x4v v0 = *(const f32x4v*)(xr + kc * 16);
            f32x4v v1 = *(const f32x4v*)(xr + kc * 16 + 4);
            union { bf16x8 v; ushort u[8]; } t;
            t.u[0] = f2bf(v0[0]); t.u[1] = f2bf(v0[1]); t.u[2] = f2bf(v0[2]); t.u[3] = f2bf(v0[3]);
            t.u[4] = f2bf(v1[0]); t.u[5] = f2bf(v1[1]); t.u[6] = f2bf(v1[2]); t.u[7] = f2bf(v1[3]);
            A[kc] = t.v;
        }
        f32x16 C0, C1;
#pragma unroll
        for (int i = 0; i < 16; i++) { C0[i] = 0.f; C1[i] = 0.f; }
#pragma unroll
        for (int kc = 0; kc < 8; kc++) {
            C0 = __builtin_amdgcn_mfma_f32_32x32x16_bf16(A[kc], B0[kc], C0, 0, 0, 0);
            C1 = __builtin_amdgcn_mfma_f32_32x32x16_bf16(A[kc], B1[kc], C1, 0, 0, 0);
        }
#pragma unroll
        for (int r = 0; r < 16; r++) {
            int rw = (r & 3) + 8 * (r >> 2) + 4 * l5;
            if (rw < nv) {
                float nm = snorm[tbase + rw];
                int   dv = sdst[tbase + rw];
                union { ushort u[2]; unsigned int w; } p;
                p.u[0] = f2bf(C0[r] * nm);
                p.u[1] = f2bf(C1[r] * nm);
                ushort* ap = agg + (size_t)dv * D + c0;   // 4B-aligned (c0 even)
                asm volatile("global_atomic_pk_add_bf16 %0, %1, off"
                             :: "v"(ap), "v"(p.w) : "memory");
            }
        }
    }
}

// ---------------- legacy edge kernel (fp32 atomics into out) ----------------
__global__ __launch_bounds__(256) void k_edge(
    const float* __restrict__ x, const ushort* __restrict__ MT,
    const int* __restrict__ starts, const int* __restrict__ ssrc,
    const int* __restrict__ sdst, const float* __restrict__ snorm,
    float* __restrict__ out) {
    int wid  = threadIdx.x >> 6, lane = threadIdx.x & 63;
    int l31  = lane & 31, l5 = lane >> 5;
    int bucket = blockIdx.x / BPB;
    int sib    = (blockIdx.x % BPB) * 2 + (wid >> 1);
    int oh     = wid & 1;
    int bstart = starts[bucket], bend = starts[bucket + 1];
    const ushort* MTb = MT + (size_t)bucket * (D * D);
    int ocol0 = oh * 64 + l31, ocol1 = oh * 64 + 32 + l31;
    bf16x8 B0[8], B1[8];
#pragma unroll
    for (int kc = 0; kc < 8; kc++) {
        B0[kc] = *(const bf16x8*)&MTb[(size_t)ocol0 * D + kc * 16 + l5 * 8];
        B1[kc] = *(const bf16x8*)&MTb[(size_t)ocol1 * D + kc * 16 + l5 * 8];
    }
    for (int tbase = bstart + sib * 32; tbase < bend; tbase += BPB * 2 * 32) {
        int nv = bend - tbase; if (nv > 32) nv = 32;
        int sr = ssrc[tbase + (l31 < nv ? l31 : 0)];
        const float* xr = x + (size_t)sr * D + l5 * 8;
        bf16x8 A[8];
#pragma unroll
        for (int kc = 0; kc < 8; kc++) {
            f32x4v v0 = *(const f32x4v*)(xr + kc * 16);
            f32x4v v1 = *(const f32x4v*)(xr + kc * 16 + 4);
            union { bf16x8 v; ushort u[8]; } t;
            t.u[0] = f2bf(v0[0]); t.u[1] = f2bf(v0[1]); t.u[2] = f2bf(v0[2]); t.u[3] = f2bf(v0[3]);
            t.u[4] = f2bf(v1[0]); t.u[5] = f2bf(v1[1]); t.u[6] = f2bf(v1[2]); t.u[7] = f2bf(v1[3]);
            A[kc] = t.v;
        }
        f32x16 C0, C1;
#pragma unroll
        for (int i = 0; i < 16; i++) { C0[i] = 0.f; C1[i] = 0.f; }
#pragma unroll
        for (int kc = 0; kc < 8; kc++) {
            C0 = __builtin_amdgcn_mfma_f32_32x32x16_bf16(A[kc], B0[kc], C0, 0, 0, 0);
            C1 = __builtin_amdgcn_mfma_f32_32x32x16_bf16(A[kc], B1[kc], C1, 0, 0, 0);
        }
#pragma unroll
        for (int r = 0; r < 16; r++) {
            int rw = (r & 3) + 8 * (r >> 2) + 4 * l5;
            if (rw < nv) {
                float nm = snorm[tbase + rw];
                int   dv = sdst[tbase + rw];
                float* op = out + (size_t)dv * D;
                atomicAdd(op + ocol0, C0[r] * nm);
                atomicAdd(op + ocol1, C1[r] * nm);
            }
        }
    }
}

// ---------------- self-loop GEMM (MFMA), reads bf16 agg, writes fp32 out ----------------
constexpr int LOOP_GRID = 400;
__global__ __launch_bounds__(256) void k_loop_pk(
    const float* __restrict__ x, const ushort* __restrict__ MT,
    const float* __restrict__ bias, const ushort* __restrict__ agg,
    float* __restrict__ out, float* __restrict__ colsum, float* __restrict__ colsq) {
    int wid = threadIdx.x >> 6, lane = threadIdx.x & 63;
    int l31 = lane & 31, l5 = lane >> 5;
    int oh  = wid & 1;
    int strm = blockIdx.x * 2 + (wid >> 1);
    const int NSTR = LOOP_GRID * 2;
    const ushort* MTb = MT + (size_t)NBUCK * (D * D);   // Mloop at index 200
    int ocol0 = oh * 64 + l31, ocol1 = oh * 64 + 32 + l31;
    bf16x8 B0[8], B1[8];
#pragma unroll
    for (int kc = 0; kc < 8; kc++) {
        B0[kc] = *(const bf16x8*)&MTb[(size_t)ocol0 * D + kc * 16 + l5 * 8];
        B1[kc] = *(const bf16x8*)&MTb[(size_t)ocol1 * D + kc * 16 + l5 * 8];
    }
    float b0 = bias[ocol0], b1 = bias[ocol1];
    float ps0 = 0.f, pq0 = 0.f, ps1 = 0.f, pq1 = 0.f;
    const int NT = V_N / 32;   // 3125, exact
    for (int tile = strm; tile < NT; tile += NSTR) {
        int tbase = tile * 32;
        const float* xr = x + (size_t)(tbase + l31) * D + l5 * 8;
        bf16x8 A[8];
#pragma unroll
        for (int kc = 0; kc < 8; kc++) {
            f32x4v v0 = *(const f32x4v*)(xr + kc * 16);
            f32x4v v1 = *(const f32x4v*)(xr + kc * 16 + 4);
            union { bf16x8 v; ushort u[8]; } t;
            t.u[0] = f2bf(v0[0]); t.u[1] = f2bf(v0[1]); t.u[2] = f2bf(v0[2]); t.u[3] = f2bf(v0[3]);
            t.u[4] = f2bf(v1[0]); t.u[5] = f2bf(v1[1]); t.u[6] = f2bf(v1[2]); t.u[7] = f2bf(v1[3]);
            A[kc] = t.v;
        }
        f32x16 C0, C1;
#pragma unroll
        for (int i = 0; i < 16; i++) { C0[i] = 0.f; C1[i] = 0.f; }
#pragma unroll
        for (int kc = 0; kc < 8; kc++) {
            C0 = __builtin_amdgcn_mfma_f32_32x32x16_bf16(A[kc], B0[kc], C0, 0, 0, 0);
            C1 = __builtin_amdgcn_mfma_f32_32x32x16_bf16(A[kc], B1[kc], C1, 0, 0, 0);
        }
#pragma unroll
        for (int r = 0; r < 16; r++) {
            int rw = (r & 3) + 8 * (r >> 2) + 4 * l5;
            size_t i0 = (size_t)(tbase + rw) * D + ocol0;
            size_t i1 = (size_t)(tbase + rw) * D + ocol1;
            float h0 = (bf2f(agg[i0]) + C0[r]) * (1.f / 3.f) + b0;
            float h1 = (bf2f(agg[i1]) + C1[r]) * (1.f / 3.f) + b1;
            out[i0] = h0; out[i1] = h1;
            ps0 += h0; pq0 += h0 * h0;
            ps1 += h1; pq1 += h1 * h1;
        }
    }
    atomicAdd(&colsum[ocol0], ps0); atomicAdd(&colsq[ocol0], pq0);
    atomicAdd(&colsum[ocol1], ps1); atomicAdd(&colsq[ocol1], pq1);
}

// ---------------- legacy self-loop (reads fp32 agg in out, in place) ----------------
__global__ __launch_bounds__(256) void k_loop(
    const float* __restrict__ x, const ushort* __restrict__ MT,
    const float* __restrict__ bias, float* __restrict__ out,
    float* __restrict__ colsum, float* __restrict__ colsq) {
    int wid = threadIdx.x >> 6, lane = threadIdx.x & 63;
    int l31 = lane & 31, l5 = lane >> 5;
    int oh  = wid & 1;
    int strm = blockIdx.x * 2 + (wid >> 1);
    const int NSTR = LOOP_GRID * 2;
    const ushort* MTb = MT + (size_t)NBUCK * (D * D);
    int ocol0 = oh * 64 + l31, ocol1 = oh * 64 + 32 + l31;
    bf16x8 B0[8], B1[8];
#pragma unroll
    for (int kc = 0; kc < 8; kc++) {
        B0[kc] = *(const bf16x8*)&MTb[(size_t)ocol0 * D + kc * 16 + l5 * 8];
        B1[kc] = *(const bf16x8*)&MTb[(size_t)ocol1 * D + kc * 16 + l5 * 8];
    }
    float b0 = bias[ocol0], b1 = bias[ocol1];
    float ps0 = 0.f, pq0 = 0.f, ps1 = 0.f, pq1 = 0.f;
    const int NT = V_N / 32;
    for (int tile = strm; tile < NT; tile += NSTR) {
        int tbase = tile * 32;
        const float* xr = x + (size_t)(tbase + l31) * D + l5 * 8;
        bf16x8 A[8];
#pragma unroll
        for (int kc = 0; kc < 8; kc++) {
            f32x4v v0 = *(const f32x4v*)(xr + kc * 16);
            f32x4v v1 = *(const f32x4v*)(xr + kc * 16 + 4);
            union { bf16x8 v; ushort u[8]; } t;
            t.u[0] = f2bf(v0[0]); t.u[1] = f2bf(v0[1]); t.u[2] = f2bf(v0[2]); t.u[3] = f2bf(v0[3]);
            t.u[4] = f2bf(v1[0]); t.u[5] = f2bf(v1[1]); t.u[6] = f2bf(v1[2]); t.u[7] = f2bf(v1[3]);
            A[kc] = t.v;
        }
        f32x16 C0, C1;
#pragma unroll
        for (int i = 0; i < 16; i++) { C0[i] = 0.f; C1[i] = 0.f; }
#pragma unroll
        for (int kc = 0; kc < 8; kc++) {
            C0 = __builtin_amdgcn_mfma_f32_32x32x16_bf16(A[kc], B0[kc], C0, 0, 0, 0);
            C1 = __builtin_amdgcn_mfma_f32_32x32x16_bf16(A[kc], B1[kc], C1, 0, 0, 0);
        }
#pragma unroll
        for (int r = 0; r < 16; r++) {
            int rw = (r & 3) + 8 * (r >> 2) + 4 * l5;
            size_t i0 = (size_t)(tbase + rw) * D + ocol0;
            size_t i1 = (size_t)(tbase + rw) * D + ocol1;
            float h0 = (out[i0] + C0[r]) * (1.f / 3.f) + b0;
            float h1 = (out[i1] + C1[r]) * (1.f / 3.f) + b1;
            out[i0] = h0; out[i1] = h1;
            ps0 += h0; pq0 += h0 * h0;
            ps1 += h1; pq1 += h1 * h1;
        }
    }
    atomicAdd(&colsum[ocol0], ps0); atomicAdd(&colsq[ocol0], pq0);
    atomicAdd(&colsum[ocol1], ps1); atomicAdd(&colsq[ocol1], pq1);
}

// ---------------- BatchNorm normalize in place ----------------
__global__ void k_bn(float* __restrict__ out, const float* __restrict__ colsum,
                     const float* __restrict__ colsq, const float* __restrict__ gamma,
                     const float* __restrict__ beta) {
    const size_t N4 = (size_t)V_N * D / 4;
    size_t stride = (size_t)gridDim.x * blockDim.x;
    for (size_t q = (size_t)blockIdx.x * blockDim.x + threadIdx.x; q < N4; q += stride) {
        int c4 = (int)(q & 31);
        float4 s  = *(const float4*)&colsum[c4 * 4];
        float4 sq = *(const float4*)&colsq[c4 * 4];
        float4 g  = *(const float4*)&gamma[c4 * 4];
        float4 be = *(const float4*)&beta[c4 * 4];
        float4 h  = *(float4*)&out[q * 4];
        const float inv = 1.f / (float)V_N;
        float m0 = s.x * inv, m1 = s.y * inv, m2 = s.z * inv, m3 = s.w * inv;
        float r0 = rsqrtf(sq.x * inv - m0 * m0 + BN_EPS_F);
        float r1 = rsqrtf(sq.y * inv - m1 * m1 + BN_EPS_F);
        float r2 = rsqrtf(sq.z * inv - m2 * m2 + BN_EPS_F);
        float r3 = rsqrtf(sq.w * inv - m3 * m3 + BN_EPS_F);
        h.x = (h.x - m0) * r0 * g.x + be.x;
        h.y = (h.y - m1) * r1 * g.y + be.y;
        h.z = (h.z - m2) * r2 * g.z + be.z;
        h.w = (h.w - m3) * r3 * g.w + be.w;
        *(float4*)&out[q * 4] = h;
    }
}

extern "C" void kernel_launch(void* const* d_in, const int* in_sizes, int n_in,
                              void* d_out, int out_size, void* d_ws, size_t ws_size,
                              hipStream_t stream) {
    const float* x        = (const float*)d_in[0];
    const float* rel      = (const float*)d_in[1];
    const float* enorm    = (const float*)d_in[2];
    const float* in_w     = (const float*)d_in[3];
    const float* out_w    = (const float*)d_in[4];
    const float* loop_w   = (const float*)d_in[5];
    const float* w_rel    = (const float*)d_in[6];
    const float* loop_rel = (const float*)d_in[7];
    const float* bias     = (const float*)d_in[8];
    const float* gamma    = (const float*)d_in[9];
    const float* beta     = (const float*)d_in[10];
    const int*   esrc     = (const int*)d_in[11];
    const int*   edst     = (const int*)d_in[12];
    const int*   etype    = (const int*)d_in[13];
    float* out = (float*)d_out;
    char*  ws  = (char*)d_ws;

    int gM = 201, smem = (D * D + 256) * sizeof(float);

    if (ws_size >= WS_NEED_PK) {
        // ---------- pk-bf16 path ----------
        ushort* MT       = (ushort*)(ws + 0);
        int*    ssrc     = (int*)(ws + P_SS_OFF);
        int*    sdst     = (int*)(ws + P_SD_OFF);
        float*  snorm    = (float*)(ws + P_SN_OFF);
        ushort* aggbf    = (ushort*)(ws + P_AGG_OFF);
        int*    hist     = (int*)(ws + P_HIST_OFF);   // overlays agg (dead after sort)
        int*    chunkoff = (int*)(ws + P_COFF_OFF);
        float*  colsum   = (float*)(ws + P_CS_OFF);
        float*  colsq    = (float*)(ws + P_CQ_OFF);
        int*    counts   = (int*)(ws + P_CNT_OFF);
        int*    starts   = (int*)(ws + P_ST_OFF);

        hipMemsetAsync(ws + P_CS_OFF, 0, 1024, stream);   // colsum+colsq

        k_hist_chunk<<<NCHUNK, 256, 0, stream>>>(etype, hist);
        k_scan_bucket<<<NBUCK, 64, 0, stream>>>(hist, chunkoff, counts);
        k_scan<<<1, 256, 0, stream>>>(counts, starts);
        k_scatter2<<<NCHUNK, 256, 0, stream>>>(esrc, edst, enorm, etype, starts, chunkoff,
                                               ssrc, sdst, snorm);
        // hist/chunkoff dead now; zero the (overlaid) agg buffer, stream-ordered
        hipMemsetAsync(ws + P_AGG_OFF, 0, AGG_BYTES, stream);

        k_build_M<<<gM, 256, smem, stream>>>(rel, in_w, out_w, loop_rel, loop_w, MT);
        k_relw<<<NREL2, D, 0, stream>>>(rel, w_rel, out + (size_t)V_N * D);

        k_edge_pk<<<NBUCK * BPB, 256, 0, stream>>>(x, MT, starts, ssrc, sdst, snorm, aggbf);
        k_loop_pk<<<LOOP_GRID, 256, 0, stream>>>(x, MT, bias, aggbf, out, colsum, colsq);
        k_bn<<<2048, 256, 0, stream>>>(out, colsum, colsq, gamma, beta);
    } else {
        // ---------- legacy (R5) path ----------
        ushort* MT       = (ushort*)(ws + M_OFF);
        int*    hist     = (int*)(ws + HIST_OFF);
        int*    chunkoff = (int*)(ws + COFF_OFF);
        int*    ssrc     = (int*)(ws + SS_OFF);
        int*    sdst     = (int*)(ws + SD_OFF);
        float*  snorm    = (float*)(ws + SN_OFF);
        int*    counts   = (int*)(ws + CNT_OFF);
        float*  colsum   = (float*)(ws + CS_OFF);
        float*  colsq    = (float*)(ws + CQ_OFF);
        int*    starts   = (int*)(ws + ST_OFF);

        hipMemsetAsync(out, 0, (size_t)V_N * D * sizeof(float), stream);
        hipMemsetAsync(ws + ZERO_OFF, 0, ZERO_BYTES, stream);

        k_hist_chunk<<<NCHUNK, 256, 0, stream>>>(etype, hist);
        k_scan_bucket<<<NBUCK, 64, 0, stream>>>(hist, chunkoff, counts);
        k_scan<<<1, 256, 0, stream>>>(counts, starts);
        k_scatter2<<<NCHUNK, 256, 0, stream>>>(esrc, edst, enorm, etype, starts, chunkoff,
                                               ssrc, sdst, snorm);

        k_build_M<<<gM, 256, smem, stream>>>(rel, in_w, out_w, loop_rel, loop_w, MT);
        k_relw<<<NREL2, D, 0, stream>>>(rel, w_rel, out + (size_t)V_N * D);

        k_edge<<<NBUCK * BPB, 256, 0, stream>>>(x, MT, starts, ssrc, sdst, snorm, out);
        k_loop<<<LOOP_GRID, 256, 0, stream>>>(x, MT, bias, out, colsum, colsq);
        k_bn<<<2048, 256, 0, stream>>>(out, colsum, colsq, gamma, beta);
    }
}